// Round 4
// baseline (3567.528 us; speedup 1.0000x reference)
//
#include <hip/hip_runtime.h>

#define B_    1024
#define T_    256
#define LOCN  40001
#define E_    100
#define H_    100
#define NC    600   // [0,400): gates (i|f|g|o) preact, [400,500): t preact, [500,600): s preact

// Sigmoid: fast exp (v_exp_f32, ~2 ulp), PRECISE division (round-3 absmax margin
// was too thin with v_rcp). tanh via 2*sig(2x)-1.
__device__ __forceinline__ float fsig(float x) {
    return 1.f / (1.f + __expf(-x));
}
__device__ __forceinline__ float ftanh(float x) {
    return 2.f / (1.f + __expf(-2.f * x)) - 1.f;
}

// ---------------------------------------------------------------------------
// Kernel 1: P_loc[LOC][600] = emb_loc @ [W_ih | W_xt | W_xs] + [b | b_t | b_s]
// ---------------------------------------------------------------------------
constexpr int PROWS = 16;
constexpr int PPAD  = 20;

__global__ __launch_bounds__(320) void proj_loc_kernel(
    const float* __restrict__ emb_loc,
    const float* __restrict__ W_ih,   // [100][400]
    const float* __restrict__ W_xt,   // [100][100]
    const float* __restrict__ W_xs,   // [100][100]
    const float* __restrict__ b,      // [400]
    const float* __restrict__ b_t,    // [100]
    const float* __restrict__ b_s,    // [100]
    float* __restrict__ P)            // [LOC][600]
{
    __shared__ __attribute__((aligned(16))) float aT[E_][PPAD];
    const int tid  = threadIdx.x;
    const int row0 = blockIdx.x * PROWS;

    for (int i = tid; i < PROWS * E_; i += 320) {
        int r = i / E_, k = i - r * E_;
        int rr = row0 + r;
        float v = 0.f;
        if (rr < LOCN) v = emb_loc[rr * E_ + k];
        aT[k][r] = v;
    }
    __syncthreads();
    if (tid >= 300) return;

    for (int cc = 0; cc < 2; ++cc) {
        const int c = tid + cc * 300;
        const float* wp; int stride; float bias;
        if (c < 400)      { wp = W_ih + c;         stride = 400; bias = b[c]; }
        else if (c < 500) { wp = W_xt + (c - 400); stride = 100; bias = b_t[c - 400]; }
        else              { wp = W_xs + (c - 500); stride = 100; bias = b_s[c - 500]; }

        float acc[PROWS];
        #pragma unroll
        for (int r = 0; r < PROWS; ++r) acc[r] = bias;

        for (int k = 0; k < E_; ++k) {
            float w = wp[(size_t)k * stride];
            #pragma unroll
            for (int r = 0; r < PROWS; ++r) acc[r] += aT[k][r] * w;
        }
        #pragma unroll
        for (int r = 0; r < PROWS; ++r) {
            int rr = row0 + r;
            if (rr < LOCN) P[(size_t)rr * NC + c] = acc[r];
        }
    }
}

// ---------------------------------------------------------------------------
// Kernel 2: P_t[92][100] = emb_t @ W_tt ; P_s[92][100] = emb_s @ W_ss
// ---------------------------------------------------------------------------
__global__ void proj_ts_kernel(
    const float* __restrict__ emb_t, const float* __restrict__ emb_s,
    const float* __restrict__ W_tt,  const float* __restrict__ W_ss,
    float* __restrict__ P_t, float* __restrict__ P_s)
{
    int idx = blockIdx.x * 256 + threadIdx.x;
    if (idx >= 2 * 92 * H_) return;
    int which = idx / (92 * H_);
    int rem   = idx - which * (92 * H_);
    int r = rem / H_, c = rem - r * H_;
    const float* e = which ? emb_s : emb_t;
    const float* W = which ? W_ss : W_tt;
    float acc = 0.f;
    #pragma unroll
    for (int k = 0; k < 12; ++k) acc += e[r * 12 + k] * W[k * H_ + c];
    (which ? P_s : P_t)[rem] = acc;
}

// ---------------------------------------------------------------------------
// Kernel 3: the recurrence. grid = 256 blocks (1/CU), 4 batch rows/block,
// 1024 threads (16 waves = exactly 4/EU).
//   tid [0,800)    : gemm. quad q=tid>>2 owns cols {2q,2q+1}; lane s=tid&3 owns
//                    k-chunk s: sizes {28,24,24,24}, starts {0,28,52,76}
//                    (16B-aligned). w zero-padded past each chunk's true size
//                    (round-3 bug: the 28-wide loop double-counted k 52-55 &
//                    76-79; now w[j>=24]=0 for s>0).
//   tid [800,1000) : t/s preact channels
//   tid [1000,1004): traj prefetch for t+1
//   epilogue       : tid<400 (c,h update)
// waves_per_eu(4,4): pin allocator to 128-reg budget (w=56 + ~40 live ≈ 95).
// Round-3 lesson: with a loose min bound the allocator chose 64 regs and
// REMATERIALIZED the invariant W_hh loads inside the step loop (7.5 GB HBM).
// ---------------------------------------------------------------------------
constexpr int RB = 4;
constexpr int NT = 1024;
constexpr int KP = 28;            // padded per-lane k-chunk
constexpr int HPAD = 104;         // h row padded: max read dword 76+27=103

__global__ __launch_bounds__(NT)
__attribute__((amdgpu_waves_per_eu(4, 4)))
void lstm_rec_kernel(
    const int* __restrict__ traj,
    const int* __restrict__ traj_len_p,
    const int* __restrict__ tu,      const int* __restrict__ tl,
    const int* __restrict__ tu_slot, const int* __restrict__ tl_slot,
    const int* __restrict__ su,      const int* __restrict__ sl,
    const int* __restrict__ su_slot, const int* __restrict__ sl_slot,
    const float* __restrict__ P,     // [LOC][600]
    const float* __restrict__ P_t,   // [92][100]
    const float* __restrict__ P_s,   // [92][100]
    const float* __restrict__ W_hh,  // [100][400]
    float* __restrict__ out)         // [B][100]
{
    __shared__ __attribute__((aligned(16))) float h_lds[RB][HPAD];
    __shared__ float gates_lds[RB][400];
    __shared__ float tg_lds[RB][H_];
    __shared__ float sg_lds[RB][H_];
    __shared__ int   loc_lds[2][RB];

    const int tid = threadIdx.x;
    const int b0  = blockIdx.x * RB;
    int steps = traj_len_p[0] + 1;
    if (steps > T_) steps = T_;

    const int s   = tid & 3;                     // k-chunk id
    const int q   = tid >> 2;                    // 0..199 for gemm threads
    const int n0  = ((tid < 800) ? q : 0) * 2;   // clamped so ALL threads load safely
    const int k0  = (s == 0) ? 0 : 4 + 24 * s;   // 0,28,52,76
    const int ksz = (s == 0) ? 28 : 24;          // true chunk size

    // W_hh slice -> 56 VGPRs (2 cols x 28 k, zero-padded past chunk & past k=99).
    // Unconditional straight-line init, literal indices after unroll.
    float w[2 * KP];
    #pragma unroll
    for (int j = 0; j < KP; ++j) {
        const int k = k0 + j;
        const bool ok = (j < ksz) && (k < H_);
        w[j]      = ok ? W_hh[k * 400 + n0]     : 0.f;
        w[KP + j] = ok ? W_hh[k * 400 + n0 + 1] : 0.f;
    }

    // zero h (incl. pad region, never rewritten)
    if (tid < RB * HPAD) ((float*)h_lds)[tid] = 0.f;
    if (tid < RB) loc_lds[0][tid] = traj[(b0 + tid) * T_];

    // lane s finalizes results ri = s and s+4; ri -> (col = n0+(ri&1), row = ri>>1)
    const int er = tid / 100;        // epilogue row   (valid for tid<400)
    const int eh = tid - er * 100;   // epilogue h-idx
    float c_reg = 0.f, hval = 0.f;
    __syncthreads();

    for (int t = 0; t < steps; ++t) {
        const int buf = t & 1;

        if (tid >= 1000) {                      // prefetch next step's locations
            int r = tid - 1000;
            if (r < RB && t + 1 < steps) loc_lds[buf ^ 1][r] = traj[(b0 + r) * T_ + t + 1];
        }

        if (tid < 800) {                        // ---- gates: K-split h @ W_hh ----
            const int riA = s, riB = s + 4;
            const int cA = riA & 1, rA = riA >> 1;
            const int cB = riB & 1, rB2 = riB >> 1;
            float gA = P[(size_t)loc_lds[buf][rA] * NC + n0 + cA];
            float gB = P[(size_t)loc_lds[buf][rB2] * NC + n0 + cB];

            float acc[2][RB];
            #pragma unroll
            for (int c = 0; c < 2; ++c)
                #pragma unroll
                for (int r = 0; r < RB; ++r) acc[c][r] = 0.f;

            #pragma unroll
            for (int j4 = 0; j4 < KP / 4; ++j4) {
                #pragma unroll
                for (int r = 0; r < RB; ++r) {
                    float4 hv = *(const float4*)(&h_lds[r][k0 + j4 * 4]);
                    #pragma unroll
                    for (int c = 0; c < 2; ++c) {
                        acc[c][r] = fmaf(hv.x, w[c * KP + j4 * 4 + 0], acc[c][r]);
                        acc[c][r] = fmaf(hv.y, w[c * KP + j4 * 4 + 1], acc[c][r]);
                        acc[c][r] = fmaf(hv.z, w[c * KP + j4 * 4 + 2], acc[c][r]);
                        acc[c][r] = fmaf(hv.w, w[c * KP + j4 * 4 + 3], acc[c][r]);
                    }
                }
            }
            // combine the 4 k-chunks within the quad (DPP shuffles)
            #pragma unroll
            for (int c = 0; c < 2; ++c)
                #pragma unroll
                for (int r = 0; r < RB; ++r) {
                    float v = acc[c][r];
                    v += __shfl_xor(v, 1);
                    v += __shfl_xor(v, 2);
                    acc[c][r] = v;
                }
            // this lane finalizes its 2 results
            {
                float vA = acc[cA][rA] + gA;
                float vB = acc[cB][rB2] + gB;
                const int colA = n0 + cA, colB = n0 + cB;
                gates_lds[rA][colA]  = (colA >= 200 && colA < 300) ? ftanh(vA) : fsig(vA);
                gates_lds[rB2][colB] = (colB >= 200 && colB < 300) ? ftanh(vB) : fsig(vB);
            }
        }

        if (tid >= 800 && tid < 1000) {         // ---- t/s gates (h-independent) ----
            const int  ch   = tid - 800;        // 0..199
            const bool is_t = ch < 100;
            const int  hx   = is_t ? ch : ch - 100;
            const int* up_a = is_t ? tu_slot : su_slot;
            const int* lo_a = is_t ? tl_slot : sl_slot;
            const int* ui_a = is_t ? tu : su;
            const int* li_a = is_t ? tl : sl;
            const float* Pq = is_t ? P_t : P_s;
            float* dst      = is_t ? &tg_lds[0][0] : &sg_lds[0][0];
            #pragma unroll
            for (int r = 0; r < RB; ++r) {
                const int off = (b0 + r) * T_ + t;
                float gp  = P[(size_t)loc_lds[buf][r] * NC + 400 + ch];
                float up  = (float)up_a[off];
                float low = (float)lo_a[off];
                int   ui  = ui_a[off], li = li_a[off];
                float iv  = (up * Pq[li * H_ + hx] + low * Pq[ui * H_ + hx])
                            / fmaxf(up + low, 1.f);
                dst[r * H_ + hx] = fsig(gp + iv);
            }
        }
        __syncthreads();

        if (tid < 400) {                        // ---- epilogue: c,h update ----
            float i_g = gates_lds[er][eh];
            float f_g = gates_lds[er][100 + eh];
            float g_g = gates_lds[er][200 + eh];
            float o_g = gates_lds[er][300 + eh];
            float tsg = tg_lds[er][eh] * sg_lds[er][eh];
            c_reg = f_g * c_reg + i_g * tsg * g_g;
            hval  = o_g * ftanh(c_reg);
            h_lds[er][eh] = hval;
        }
        __syncthreads();
    }

    if (tid < 400) out[b0 * H_ + tid] = hval;
}

// ---------------------------------------------------------------------------
extern "C" void kernel_launch(void* const* d_in, const int* in_sizes, int n_in,
                              void* d_out, int out_size, void* d_ws, size_t ws_size,
                              hipStream_t stream) {
    const int*   traj     = (const int*)  d_in[0];
    const int*   traj_len = (const int*)  d_in[2];
    const int*   tu       = (const int*)  d_in[3];
    const int*   tl       = (const int*)  d_in[4];
    const int*   tu_slot  = (const int*)  d_in[5];
    const int*   tl_slot  = (const int*)  d_in[6];
    const int*   su       = (const int*)  d_in[7];
    const int*   sl       = (const int*)  d_in[8];
    const int*   su_slot  = (const int*)  d_in[9];
    const int*   sl_slot  = (const int*)  d_in[10];
    const float* emb_loc  = (const float*)d_in[11];
    const float* emb_t    = (const float*)d_in[12];
    const float* emb_s    = (const float*)d_in[13];
    const float* W_ih     = (const float*)d_in[14];
    const float* W_hh     = (const float*)d_in[15];
    const float* b        = (const float*)d_in[16];
    const float* W_xt     = (const float*)d_in[17];
    const float* W_tt     = (const float*)d_in[18];
    const float* b_t      = (const float*)d_in[19];
    const float* W_xs     = (const float*)d_in[20];
    const float* W_ss     = (const float*)d_in[21];
    const float* b_s      = (const float*)d_in[22];

    float* P   = (float*)d_ws;              // 40001*600 floats (96.0 MB)
    float* P_t = P + (size_t)LOCN * NC;
    float* P_s = P_t + 92 * H_;

    proj_loc_kernel<<<(LOCN + PROWS - 1) / PROWS, 320, 0, stream>>>(
        emb_loc, W_ih, W_xt, W_xs, b, b_t, b_s, P);
    proj_ts_kernel<<<(2 * 92 * H_ + 255) / 256, 256, 0, stream>>>(
        emb_t, emb_s, W_tt, W_ss, P_t, P_s);
    lstm_rec_kernel<<<B_ / RB, NT, 0, stream>>>(
        traj, traj_len, tu, tl, tu_slot, tl_slot, su, sl, su_slot, sl_slot,
        P, P_t, P_s, W_hh, (float*)d_out);
}

// Round 5
// 1325.221 us; speedup vs baseline: 2.6920x; 2.6920x over previous
//
#include <hip/hip_runtime.h>

#define B_    1024
#define T_    256
#define LOCN  40001
#define E_    100
#define H_    100
#define NC    600
// P layout: cols [0,400) = gate preacts INTERLEAVED as c' = (c%100)*4 + c/100
// (so {i,f,g,o} for hidden unit eh are adjacent -> one float4 gather);
// [400,500) t-preact; [500,600) s-preact.

typedef __attribute__((ext_vector_type(8))) short short8;
typedef __attribute__((ext_vector_type(4))) float f32x4;

__device__ __forceinline__ float fsig(float x)  { return 1.f / (1.f + __expf(-x)); }
__device__ __forceinline__ float ftanh(float x) { return 2.f / (1.f + __expf(-2.f * x)) - 1.f; }

__device__ __forceinline__ unsigned short bf16_rne(float f) {
    unsigned int u = __float_as_uint(f);
    unsigned int r = u + 0x7fffu + ((u >> 16) & 1u);
    return (unsigned short)(r >> 16);
}
__device__ __forceinline__ float bf16_to_f(unsigned short h) {
    return __uint_as_float(((unsigned int)h) << 16);
}

// ---------------------------------------------------------------------------
// Kernel 1: P_loc = emb_loc @ [W_ih | W_xt | W_xs] + biases (gate cols interleaved)
// ---------------------------------------------------------------------------
constexpr int PROWS = 16;
constexpr int PPAD  = 20;

__global__ __launch_bounds__(320) void proj_loc_kernel(
    const float* __restrict__ emb_loc,
    const float* __restrict__ W_ih, const float* __restrict__ W_xt,
    const float* __restrict__ W_xs,
    const float* __restrict__ b, const float* __restrict__ b_t,
    const float* __restrict__ b_s,
    float* __restrict__ P)
{
    __shared__ __attribute__((aligned(16))) float aT[E_][PPAD];
    const int tid  = threadIdx.x;
    const int row0 = blockIdx.x * PROWS;

    for (int i = tid; i < PROWS * E_; i += 320) {
        int r = i / E_, k = i - r * E_;
        int rr = row0 + r;
        float v = 0.f;
        if (rr < LOCN) v = emb_loc[rr * E_ + k];
        aT[k][r] = v;
    }
    __syncthreads();
    if (tid >= 300) return;

    for (int cc = 0; cc < 2; ++cc) {
        const int c = tid + cc * 300;
        const float* wp; int stride; float bias;
        if (c < 400)      { wp = W_ih + c;         stride = 400; bias = b[c]; }
        else if (c < 500) { wp = W_xt + (c - 400); stride = 100; bias = b_t[c - 400]; }
        else              { wp = W_xs + (c - 500); stride = 100; bias = b_s[c - 500]; }

        float acc[PROWS];
        #pragma unroll
        for (int r = 0; r < PROWS; ++r) acc[r] = bias;

        for (int k = 0; k < E_; ++k) {
            float w = wp[(size_t)k * stride];
            #pragma unroll
            for (int r = 0; r < PROWS; ++r) acc[r] += aT[k][r] * w;
        }
        const int cs = (c < 400) ? ((c % 100) * 4 + c / 100) : c;  // interleave gates
        #pragma unroll
        for (int r = 0; r < PROWS; ++r) {
            int rr = row0 + r;
            if (rr < LOCN) P[(size_t)rr * NC + cs] = acc[r];
        }
    }
}

// ---------------------------------------------------------------------------
// Kernel 2: P_t = emb_t @ W_tt ; P_s = emb_s @ W_ss
// ---------------------------------------------------------------------------
__global__ void proj_ts_kernel(
    const float* __restrict__ emb_t, const float* __restrict__ emb_s,
    const float* __restrict__ W_tt,  const float* __restrict__ W_ss,
    float* __restrict__ P_t, float* __restrict__ P_s)
{
    int idx = blockIdx.x * 256 + threadIdx.x;
    if (idx >= 2 * 92 * H_) return;
    int which = idx / (92 * H_);
    int rem   = idx - which * (92 * H_);
    int r = rem / H_, c = rem - r * H_;
    const float* e = which ? emb_s : emb_t;
    const float* W = which ? W_ss : W_tt;
    float acc = 0.f;
    #pragma unroll
    for (int k = 0; k < 12; ++k) acc += e[r * 12 + k] * W[k * H_ + c];
    (which ? P_s : P_t)[rem] = acc;
}

// ---------------------------------------------------------------------------
// Kernel 3: recurrence via split-bf16 MFMA (16x16x32).
//   D[4][400] = h[4][100] @ W_hh[100][400], 3 MFMAs per tile (hi*hi+lo*hi+hi*lo).
//   Waves 0-12: MFMA, wave wv owns n-tiles {2wv, 2wv+1} (tile = 16 gate cols).
//     B-frags (W bf16 hi/lo) converted once -> 64 VGPRs, vector-typed chain
//     (not remat-able — the round-3/4 killer).
//   A-frags (h bf16 hi/lo) staged in LDS in exact fragment order:
//     slot[kt*64+lane][j] = h[lane&15][kt*32+(lane>>4)*8+j]; 1 ds_read_b128
//     per (kt, hi/lo) per lane = bandwidth-floor reads.
//   tid [832,1020): t/s gates; tid >=1020: loc prefetch; tid<400: epilogue.
// ---------------------------------------------------------------------------
constexpr int RB = 4;
constexpr int NT = 1024;

__global__ __launch_bounds__(NT, 4)
void lstm_rec_kernel(
    const int* __restrict__ traj,
    const int* __restrict__ traj_len_p,
    const int* __restrict__ tu,      const int* __restrict__ tl,
    const int* __restrict__ tu_slot, const int* __restrict__ tl_slot,
    const int* __restrict__ su,      const int* __restrict__ sl,
    const int* __restrict__ su_slot, const int* __restrict__ sl_slot,
    const float* __restrict__ P,     // [LOC][600] (gates interleaved)
    const float* __restrict__ P_t,   // [92][100]
    const float* __restrict__ P_s,   // [92][100]
    const float* __restrict__ W_hh,  // [100][400]
    float* __restrict__ out)         // [B][100]
{
    __shared__ __attribute__((aligned(16))) unsigned int afH32[4 * 64 * 4]; // A-frag hi (bf16 pairs)
    __shared__ __attribute__((aligned(16))) unsigned int afL32[4 * 64 * 4]; // A-frag lo
    __shared__ float gates_lds[RB][400];   // h@W_hh part only
    __shared__ float tg_lds[RB][H_];
    __shared__ float sg_lds[RB][H_];
    __shared__ int   loc_lds[2][RB];

    const int tid  = threadIdx.x;
    const int lane = tid & 63;
    const int wv   = tid >> 6;
    const int b0   = blockIdx.x * RB;
    int steps = traj_len_p[0] + 1;
    if (steps > T_) steps = T_;

    // ---- B-fragments: W_hh -> bf16 hi/lo, MFMA B layout, once ----
    short8 bh[2][4], bl[2][4];   // [tile][ktile] : 64 VGPRs total
    if (wv < 13) {
        #pragma unroll
        for (int tt = 0; tt < 2; ++tt) {
            const int nt = wv * 2 + tt;
            const bool tv = (nt < 25);
            const int n = (tv ? nt : 0) * 16 + (lane & 15);
            #pragma unroll
            for (int kt = 0; kt < 4; ++kt) {
                short8 h8, l8;
                #pragma unroll
                for (int j = 0; j < 8; ++j) {
                    const int k = kt * 32 + (lane >> 4) * 8 + j;
                    const float wval = (tv && k < H_) ? W_hh[k * 400 + n] : 0.f;
                    const unsigned short hi = bf16_rne(wval);
                    const unsigned short lo = bf16_rne(wval - bf16_to_f(hi));
                    h8[j] = (short)hi; l8[j] = (short)lo;
                }
                bh[tt][kt] = h8; bl[tt][kt] = l8;
            }
        }
    }

    // zero A-frag buffers (covers h0=0, row-pad m>=4, k-pad >=100)
    afH32[tid] = 0u; afL32[tid] = 0u;
    if (tid < RB) loc_lds[0][tid] = traj[(b0 + tid) * T_];

    const int er = tid / 100;        // epilogue: batch row (valid tid<400)
    const int eh = tid - er * 100;   // epilogue: hidden idx
    float c_reg = 0.f, hval = 0.f;
    __syncthreads();

    for (int t = 0; t < steps; ++t) {
        const int buf = t & 1;

        if (tid >= 1020) {                       // prefetch next step's locations
            int r = tid - 1020;
            if (t + 1 < steps) loc_lds[buf ^ 1][r] = traj[(b0 + r) * T_ + t + 1];
        }

        // epilogue threads: issue the x-preact gather EARLY (hidden under MFMA)
        float4 pg = {0.f, 0.f, 0.f, 0.f};
        if (tid < 400) {
            const float4* prow = (const float4*)(P + (size_t)loc_lds[buf][er] * NC);
            pg = prow[eh];                       // {i,f,g,o} preacts for (er, eh)
        }

        // ---- phase 1a: MFMA ----
        if (wv < 13) {
            f32x4 acc0 = {0.f, 0.f, 0.f, 0.f};
            f32x4 acc1 = {0.f, 0.f, 0.f, 0.f};
            #pragma unroll
            for (int kt = 0; kt < 4; ++kt) {
                const int slot = kt * 64 + lane;
                short8 ah = *(const short8*)&afH32[slot * 4];
                short8 al = *(const short8*)&afL32[slot * 4];
                acc0 = __builtin_amdgcn_mfma_f32_16x16x32_bf16(ah, bh[0][kt], acc0, 0, 0, 0);
                acc0 = __builtin_amdgcn_mfma_f32_16x16x32_bf16(al, bh[0][kt], acc0, 0, 0, 0);
                acc0 = __builtin_amdgcn_mfma_f32_16x16x32_bf16(ah, bl[0][kt], acc0, 0, 0, 0);
                acc1 = __builtin_amdgcn_mfma_f32_16x16x32_bf16(ah, bh[1][kt], acc1, 0, 0, 0);
                acc1 = __builtin_amdgcn_mfma_f32_16x16x32_bf16(al, bh[1][kt], acc1, 0, 0, 0);
                acc1 = __builtin_amdgcn_mfma_f32_16x16x32_bf16(ah, bl[1][kt], acc1, 0, 0, 0);
            }
            // C layout: col = lane&15, row = (lane>>4)*4 + reg -> rows 0-3 live in lanes 0-15
            if (lane < 16) {
                const int col0 = (wv * 2) * 16 + lane;
                #pragma unroll
                for (int r = 0; r < RB; ++r) gates_lds[r][col0] = acc0[r];
                if (wv * 2 + 1 < 25) {
                    const int col1 = col0 + 16;
                    #pragma unroll
                    for (int r = 0; r < RB; ++r) gates_lds[r][col1] = acc1[r];
                }
            }
        }

        // ---- phase 1b: t/s gates (h-independent) ----
        if (tid >= 832 && tid < 1020) {
            for (int ch = tid - 832; ch < 200; ch += 188) {
                const bool is_t = ch < 100;
                const int  hx   = is_t ? ch : ch - 100;
                const int* up_a = is_t ? tu_slot : su_slot;
                const int* lo_a = is_t ? tl_slot : sl_slot;
                const int* ui_a = is_t ? tu : su;
                const int* li_a = is_t ? tl : sl;
                const float* Pq = is_t ? P_t : P_s;
                float* dst      = is_t ? &tg_lds[0][0] : &sg_lds[0][0];
                #pragma unroll
                for (int r = 0; r < RB; ++r) {
                    const int off = (b0 + r) * T_ + t;
                    float gp  = P[(size_t)loc_lds[buf][r] * NC + 400 + ch];
                    float up  = (float)up_a[off];
                    float low = (float)lo_a[off];
                    int   ui  = ui_a[off], li = li_a[off];
                    float iv  = (up * Pq[li * H_ + hx] + low * Pq[ui * H_ + hx])
                                / fmaxf(up + low, 1.f);
                    dst[r * H_ + hx] = fsig(gp + iv);
                }
            }
        }
        __syncthreads();

        // ---- phase 2: epilogue (c,h) + A-frag staging for t+1 ----
        if (tid < 400) {
            float vi = gates_lds[er][eh]       + pg.x;
            float vf = gates_lds[er][eh + 100] + pg.y;
            float vg = gates_lds[er][eh + 200] + pg.z;
            float vo = gates_lds[er][eh + 300] + pg.w;
            float ig = fsig(vi), fg = fsig(vf), gg = ftanh(vg), og = fsig(vo);
            float tsg = tg_lds[er][eh] * sg_lds[er][eh];
            c_reg = fg * c_reg + ig * tsg * gg;
            hval  = og * ftanh(c_reg);

            // write h (bf16 hi/lo) into A-frag order:
            // slot = (eh>>5)*64 + er + 16*((eh>>3)&3), halfword j = eh&7
            unsigned hb = bf16_rne(hval);
            unsigned lb = bf16_rne(hval - bf16_to_f((unsigned short)hb));
            unsigned hbn = (unsigned)__shfl_down((int)hb, 1);
            unsigned lbn = (unsigned)__shfl_down((int)lb, 1);
            if ((eh & 1) == 0) {      // even lane packs (k, k+1) -> one b32 write
                const int slot = (eh >> 5) * 64 + er + (((eh >> 3) & 3) << 4);
                const int didx = slot * 4 + ((eh & 7) >> 1);
                afH32[didx] = hb | (hbn << 16);
                afL32[didx] = lb | (lbn << 16);
            }
        }
        __syncthreads();
    }

    if (tid < 400) out[b0 * H_ + tid] = hval;
}

// ---------------------------------------------------------------------------
extern "C" void kernel_launch(void* const* d_in, const int* in_sizes, int n_in,
                              void* d_out, int out_size, void* d_ws, size_t ws_size,
                              hipStream_t stream) {
    const int*   traj     = (const int*)  d_in[0];
    const int*   traj_len = (const int*)  d_in[2];
    const int*   tu       = (const int*)  d_in[3];
    const int*   tl       = (const int*)  d_in[4];
    const int*   tu_slot  = (const int*)  d_in[5];
    const int*   tl_slot  = (const int*)  d_in[6];
    const int*   su       = (const int*)  d_in[7];
    const int*   sl       = (const int*)  d_in[8];
    const int*   su_slot  = (const int*)  d_in[9];
    const int*   sl_slot  = (const int*)  d_in[10];
    const float* emb_loc  = (const float*)d_in[11];
    const float* emb_t    = (const float*)d_in[12];
    const float* emb_s    = (const float*)d_in[13];
    const float* W_ih     = (const float*)d_in[14];
    const float* W_hh     = (const float*)d_in[15];
    const float* b        = (const float*)d_in[16];
    const float* W_xt     = (const float*)d_in[17];
    const float* W_tt     = (const float*)d_in[18];
    const float* b_t      = (const float*)d_in[19];
    const float* W_xs     = (const float*)d_in[20];
    const float* W_ss     = (const float*)d_in[21];
    const float* b_s      = (const float*)d_in[22];

    float* P   = (float*)d_ws;              // 40001*600 floats (96.0 MB)
    float* P_t = P + (size_t)LOCN * NC;
    float* P_s = P_t + 92 * H_;

    proj_loc_kernel<<<(LOCN + PROWS - 1) / PROWS, 320, 0, stream>>>(
        emb_loc, W_ih, W_xt, W_xs, b, b_t, b_s, P);
    proj_ts_kernel<<<(2 * 92 * H_ + 255) / 256, 256, 0, stream>>>(
        emb_t, emb_s, W_tt, W_ss, P_t, P_s);
    lstm_rec_kernel<<<B_ / RB, NT, 0, stream>>>(
        traj, traj_len, tu, tl, tu_slot, tl_slot, su, sl, su_slot, sl_slot,
        P, P_t, P_s, W_hh, (float*)d_out);
}